// Round 1
// baseline (270.889 us; speedup 1.0000x reference)
//
#include <hip/hip_runtime.h>
#include <stdint.h>

#define BATCH 4
#define CINCH 3
#define HIN 128
#define WIN 128
#define NN 4096      // 64*64 output nodes per batch
#define CF 64        // feature channels
#define KNN 7

// ---------------------------------------------------------------- helpers
__device__ __forceinline__ unsigned long long u64min(unsigned long long a,
                                                     unsigned long long b) {
    return a < b ? a : b;
}

// insert wave-uniform candidate k into ascending sorted 7-list (drops max)
__device__ __forceinline__ void insert7(unsigned long long* lst,
                                        unsigned long long k) {
    unsigned long long cur = k;
#pragma unroll
    for (int i = 0; i < KNN; ++i) {
        unsigned long long lo = u64min(lst[i], cur);
        unsigned long long hi = (lst[i] < cur) ? cur : lst[i];
        lst[i] = lo;
        cur = hi;
    }
}

// ------------------------------------------------ K1: conv3x3 s2 p1 -> y[B][N][C]
__global__ __launch_bounds__(256) void conv_kernel(
    const float* __restrict__ x, const float* __restrict__ w,
    const float* __restrict__ bias, float* __restrict__ y) {
    __shared__ float ws[CF * CINCH * 9];
    __shared__ float bs[CF];
    for (int i = threadIdx.x; i < CF * CINCH * 9; i += 256) ws[i] = w[i];
    if (threadIdx.x < CF) bs[threadIdx.x] = bias[threadIdx.x];
    __syncthreads();

    int gid = blockIdx.x * 256 + threadIdx.x;   // ((b*4096)+n)*64 + c
    int c = gid & 63;
    int n = (gid >> 6) & (NN - 1);
    int b = gid >> 18;
    int oh = n >> 6, ow = n & 63;
    const float* xb = x + (size_t)b * CINCH * HIN * WIN;
    float acc = bs[c];
#pragma unroll
    for (int cin = 0; cin < CINCH; ++cin) {
#pragma unroll
        for (int kh = 0; kh < 3; ++kh) {
            int ih = oh * 2 - 1 + kh;
            if (ih < 0 || ih >= HIN) continue;
#pragma unroll
            for (int kw = 0; kw < 3; ++kw) {
                int iw = ow * 2 - 1 + kw;
                if (iw < 0 || iw >= WIN) continue;
                acc += xb[(cin * HIN + ih) * WIN + iw] *
                       ws[(c * CINCH + cin) * 9 + kh * 3 + kw];
            }
        }
    }
    y[(size_t)gid] = acc;
}

// ------------------------------------------------ K2: sq[n] = sum_c y[n][c]^2
__global__ __launch_bounds__(256) void sq_kernel(const float* __restrict__ y,
                                                 float* __restrict__ sq) {
    int n = blockIdx.x * 256 + threadIdx.x;   // 0..B*NN-1
    const float4* yr = (const float4*)(y + (size_t)n * CF);
    float s = 0.f;
#pragma unroll
    for (int i = 0; i < 16; ++i) {
        float4 v = yr[i];
        s += v.x * v.x;
        s += v.y * v.y;
        s += v.z * v.z;
        s += v.w * v.w;
    }
    sq[n] = s;
}

// ------------------------------------------------ K3: dist matrix (f32 GEMM-like)
// writes dist = sqrt(max(sq_n + sq_m - 2*dot, 0)) into dbuf (= adj region, scratch)
#define MT 128
__global__ __launch_bounds__(256) void dist_kernel(const float* __restrict__ y,
                                                   const float* __restrict__ sq,
                                                   float* __restrict__ dbuf) {
    __shared__ float4 at[MT * 16];   // 32 KB, XOR-swizzled rows tile
    __shared__ float4 bt[MT * 16];   // 32 KB, XOR-swizzled cols tile

    const int b = blockIdx.z;
    const int row0 = blockIdx.y * MT;
    const int col0 = blockIdx.x * MT;
    const int tid = threadIdx.x;

    const float4* yb = (const float4*)(y + (size_t)b * NN * CF);
    const float* sqb = sq + b * NN;

    // stage both tiles; stored[v][k] = y[v][k ^ ((v>>3)&7)]
#pragma unroll
    for (int it = 0; it < 8; ++it) {
        int s = it * 256 + tid;          // 0..2047
        int v = s >> 4, k = s & 15;
        int swz = (v >> 3) & 7;
        at[v * 16 + k] = yb[(size_t)(row0 + v) * 16 + (k ^ swz)];
        bt[v * 16 + k] = yb[(size_t)(col0 + v) * 16 + (k ^ swz)];
    }
    __syncthreads();

    const int wave = tid >> 6, lane = tid & 63;
    const int lr = lane >> 3, lc = lane & 7;
    const int wr = (wave >> 1) * 64, wc = (wave & 1) * 64;

    float acc[8][8] = {};
#pragma unroll
    for (int k = 0; k < 16; ++k) {
        float4 af[8], bf[8];
#pragma unroll
        for (int i = 0; i < 8; ++i) {
            int ra = wr + lr * 8 + i;
            af[i] = at[ra * 16 + (k ^ ((ra >> 3) & 7))];
            int cb = wc + lc * 8 + i;
            bf[i] = bt[cb * 16 + (k ^ ((cb >> 3) & 7))];
        }
#pragma unroll
        for (int i = 0; i < 8; ++i)
#pragma unroll
            for (int j = 0; j < 8; ++j) {
                acc[i][j] += af[i].x * bf[j].x;
                acc[i][j] += af[i].y * bf[j].y;
                acc[i][j] += af[i].z * bf[j].z;
                acc[i][j] += af[i].w * bf[j].w;
            }
    }

    float sqr[8], sqc[8];
#pragma unroll
    for (int i = 0; i < 8; ++i) {
        sqr[i] = sqb[row0 + wr + lr * 8 + i];
        sqc[i] = sqb[col0 + wc + lc * 8 + i];
    }
#pragma unroll
    for (int i = 0; i < 8; ++i) {
        int gr = row0 + wr + lr * 8 + i;
        float4* dst = (float4*)(dbuf + ((size_t)b * NN + gr) * NN + col0 + wc + lc * 8);
        float d[8];
#pragma unroll
        for (int j = 0; j < 8; ++j) {
            float d2 = (sqr[i] + sqc[j]) - 2.0f * acc[i][j];
            d[j] = sqrtf(fmaxf(d2, 0.0f));
        }
        dst[0] = make_float4(d[0], d[1], d[2], d[3]);
        dst[1] = make_float4(d[4], d[5], d[6], d[7]);
    }
}

// ------------------------------------------------ K4: top-7 select, in-place adj
// one wave per row; key = (dist_bits << 32) | m  -> 7 lex-smallest == rank<=6
__global__ __launch_bounds__(256) void select_kernel(float* __restrict__ dbuf) {
    const int grow = (blockIdx.x * 256 + threadIdx.x) >> 6;   // 0..B*NN-1
    const int lane = threadIdx.x & 63;
    float4* row = (float4*)(dbuf + (size_t)grow * NN);

    unsigned long long lst[KNN];
#pragma unroll
    for (int i = 0; i < KNN; ++i) lst[i] = ~0ull;

    for (int ch = 0; ch < 16; ++ch) {
        float4 v = row[ch * 64 + lane];
        unsigned mb = (unsigned)(ch * 64 + lane) * 4u;
        unsigned long long k0 = ((unsigned long long)__float_as_uint(v.x) << 32) | (mb + 0u);
        unsigned long long k1 = ((unsigned long long)__float_as_uint(v.y) << 32) | (mb + 1u);
        unsigned long long k2 = ((unsigned long long)__float_as_uint(v.z) << 32) | (mb + 2u);
        unsigned long long k3 = ((unsigned long long)__float_as_uint(v.w) << 32) | (mb + 3u);
        unsigned long long lm = u64min(u64min(k0, k1), u64min(k2, k3));
        while (__ballot(lm < lst[KNN - 1]) != 0ull) {
            unsigned long long cand = (lm < lst[KNN - 1]) ? lm : ~0ull;
#pragma unroll
            for (int off = 32; off; off >>= 1)
                cand = u64min(cand, __shfl_xor(cand, off, 64));
            insert7(lst, cand);
            if (k0 == cand) k0 = ~0ull;
            if (k1 == cand) k1 = ~0ull;
            if (k2 == cand) k2 = ~0ull;
            if (k3 == cand) k3 = ~0ull;
            lm = u64min(u64min(k0, k1), u64min(k2, k3));
        }
    }

    unsigned idx[KNN];
#pragma unroll
    for (int i = 0; i < KNN; ++i) idx[i] = (unsigned)(lst[i] & 0xffffffffu);

    for (int ch = 0; ch < 16; ++ch) {
        unsigned e = (unsigned)(ch * 64 + lane) * 4u;
        float vx = 0.f, vy = 0.f, vz = 0.f, vw = 0.f;
#pragma unroll
        for (int t = 0; t < KNN; ++t) {
            unsigned d = idx[t] - e;
            vx = (d == 0u) ? 1.f : vx;
            vy = (d == 1u) ? 1.f : vy;
            vz = (d == 2u) ? 1.f : vz;
            vw = (d == 3u) ? 1.f : vw;
        }
        row[ch * 64 + lane] = make_float4(vx, vy, vz, vw);
    }
}

// ------------------------------------------------ launcher
extern "C" void kernel_launch(void* const* d_in, const int* in_sizes, int n_in,
                              void* d_out, int out_size, void* d_ws, size_t ws_size,
                              hipStream_t stream) {
    const float* x = (const float*)d_in[0];
    const float* w = (const float*)d_in[1];
    const float* bias = (const float*)d_in[2];

    float* y = (float*)d_out;                               // [4][4096][64]
    float* adj = (float*)d_out + (size_t)BATCH * NN * CF;   // [4][4096][4096]
    float* sq = (float*)d_ws;                               // 16384 floats

    conv_kernel<<<4096, 256, 0, stream>>>(x, w, bias, y);
    sq_kernel<<<64, 256, 0, stream>>>(y, sq);
    dist_kernel<<<dim3(32, 32, BATCH), 256, 0, stream>>>(y, sq, adj);
    select_kernel<<<4096, 256, 0, stream>>>(adj);
}